// Round 1
// baseline (179.994 us; speedup 1.0000x reference)
//
#include <hip/hip_runtime.h>
#include <cstdint>
#include <cstddef>

// Problem constants (fixed by setup_inputs)
#define BB 4
#define NN 8192
#define MM 4096
#define CC 64
#define SS 32
#define CH 67  // 3 (xyz) + 64 (features)

// radius^2 exactly as Python computes it: double 0.12*0.12 rounded once to f32.
__device__ __constant__ float kRR = (float)(0.12 * 0.12);

__global__ __launch_bounds__(256) void qg_fused_kernel(
    const float* __restrict__ xyz,      // (B,N,3)
    const float* __restrict__ new_xyz,  // (B,M,3)
    const float* __restrict__ feat,     // (B,C,N)
    float* __restrict__ out)            // (B,67,M,32)
{
    const int wave = (int)((blockIdx.x * blockDim.x + threadIdx.x) >> 6);
    const int lane = (int)(threadIdx.x & 63);
    const int b = wave / MM;
    const int m = wave % MM;

    const float* __restrict__ xb = xyz + (size_t)b * NN * 3;
    const size_t qoff = ((size_t)b * MM + m) * 3;
    const float cx = new_xyz[qoff + 0];
    const float cy = new_xyz[qoff + 1];
    const float cz = new_xyz[qoff + 2];
    const float rr = kRR;

    // Slot p (p < 32) lives in lane p's my_nb register.
    int my_nb = -1;
    int cnt = 0;

    for (int base = 0; base < NN; base += 64) {
        const int i = base + lane;
        // exact f32 ops, no FMA contraction, to match XLA's mask bit-for-bit
        const float dx = __fsub_rn(xb[i * 3 + 0], cx);
        const float dy = __fsub_rn(xb[i * 3 + 1], cy);
        const float dz = __fsub_rn(xb[i * 3 + 2], cz);
        const float d2 = __fadd_rn(__fadd_rn(__fmul_rn(dx, dx), __fmul_rn(dy, dy)),
                                   __fmul_rn(dz, dz));
        const unsigned long long mask = __ballot(d2 < rr);  // uniform across wave
        const int pc = __popcll(mask);
        if (pc) {
            // Lane p takes the (p-cnt)-th set bit of mask as its neighbor index.
            const int need = lane - cnt;
            if (lane >= cnt && lane < SS && need < pc) {
                unsigned long long mm = mask;
                for (int k = 0; k < need; ++k) mm &= (mm - 1);  // clear `need` lowest bits
                my_nb = base + (int)__builtin_ctzll(mm);
            }
            cnt += pc;                 // uniform
            if (cnt >= SS) break;      // uniform break
        }
    }

    // Padding: slots past the found count get the first found index (or 0 if none).
    int first = __shfl(my_nb, 0);
    if (first < 0) first = 0;
    if (lane < SS && my_nb < 0) my_nb = first;

    // All 64 lanes fetch slot (lane & 31)'s neighbor index.
    const int n_of = __shfl(my_nb, lane & 31);

    // Gather + write: lanes 0-31 handle channel cc, lanes 32-63 channel cc+1.
    const int s = lane & 31;
    const int chalf = lane >> 5;
    const size_t out_base = (((size_t)b * CH) * MM + m) * SS + s;
    const float* __restrict__ fb = feat + (size_t)b * CC * NN;

    #pragma unroll 2
    for (int cc = 0; cc < CH + 1; cc += 2) {
        const int c = cc + chalf;
        if (c < CH) {
            float v;
            if (c < 3) {
                const float center = (c == 0) ? cx : (c == 1) ? cy : cz;
                v = __fsub_rn(xb[(size_t)n_of * 3 + c], center);
            } else {
                v = fb[(size_t)(c - 3) * NN + n_of];
            }
            out[out_base + (size_t)c * (MM * SS)] = v;
        }
    }
}

extern "C" void kernel_launch(void* const* d_in, const int* in_sizes, int n_in,
                              void* d_out, int out_size, void* d_ws, size_t ws_size,
                              hipStream_t stream) {
    const float* xyz     = (const float*)d_in[0];  // (4,8192,3)
    const float* new_xyz = (const float*)d_in[1];  // (4,4096,3)
    const float* feat    = (const float*)d_in[2];  // (4,64,8192)
    float* out = (float*)d_out;                    // (4,67,4096,32)

    // One wave per query: B*M = 16384 waves; 4 waves per 256-thread block.
    const int total_waves = BB * MM;
    const int blocks = total_waves / 4;
    qg_fused_kernel<<<blocks, 256, 0, stream>>>(xyz, new_xyz, feat, out);
}

// Round 2
// 167.091 us; speedup vs baseline: 1.0772x; 1.0772x over previous
//
#include <hip/hip_runtime.h>
#include <cstdint>
#include <cstddef>

// Problem constants (fixed by setup_inputs)
#define BB 4
#define NN 8192
#define MM 4096
#define CC 64
#define SS 32
#define CH 67      // 3 (xyz) + 64 (features)
#define UNROLL 8   // chunks per super-iteration: 8 * 64 = 512 points

// radius^2 exactly as Python computes it: double 0.12*0.12 rounded once to f32.
__device__ __constant__ float kRR = (float)(0.12 * 0.12);

__global__ __launch_bounds__(256) void qg_fused_kernel(
    const float* __restrict__ xyz,      // (B,N,3)
    const float* __restrict__ new_xyz,  // (B,M,3)
    const float* __restrict__ feat,     // (B,C,N)
    float* __restrict__ out)            // (B,67,M,32)
{
    const int wave = (int)((blockIdx.x * blockDim.x + threadIdx.x) >> 6);
    const int lane = (int)(threadIdx.x & 63);
    const int b = wave / MM;
    const int m = wave % MM;

    const float* __restrict__ xb = xyz + (size_t)b * NN * 3;
    const size_t qoff = ((size_t)b * MM + m) * 3;
    const float cx = new_xyz[qoff + 0];
    const float cy = new_xyz[qoff + 1];
    const float cz = new_xyz[qoff + 2];
    const float rr = kRR;

    // Slot p (p < 32) lives in lane p's my_nb register.
    int my_nb = -1;
    int cnt = 0;

    for (int base = 0; base < NN; base += UNROLL * 64) {
        // Issue all UNROLL chunks' loads before any processing: independent,
        // so they overlap in flight (breaks the load->ballot->break serial chain).
        float px[UNROLL], py[UNROLL], pz[UNROLL];
        #pragma unroll
        for (int k = 0; k < UNROLL; ++k) {
            const int i = base + (k << 6) + lane;
            px[k] = xb[i * 3 + 0];
            py[k] = xb[i * 3 + 1];
            pz[k] = xb[i * 3 + 2];
        }
        #pragma unroll
        for (int k = 0; k < UNROLL; ++k) {
            // exact f32 ops, no FMA contraction, to match XLA's mask bit-for-bit
            const float dx = __fsub_rn(px[k], cx);
            const float dy = __fsub_rn(py[k], cy);
            const float dz = __fsub_rn(pz[k], cz);
            const float d2 = __fadd_rn(__fadd_rn(__fmul_rn(dx, dx), __fmul_rn(dy, dy)),
                                       __fmul_rn(dz, dz));
            const bool hit = d2 < rr;
            const unsigned long long mask = __ballot(hit);  // uniform across wave
            const int pc = __popcll(mask);
            if (pc) {
                // rank of this lane's hit among [cnt, cnt+pc)
                const int rank = cnt + (int)__popcll(mask & ((1ull << lane) - 1ull));
                // push my index to slot-lane `rank` (non-hit lanes dump to lane 63)
                const int addr = (hit && rank < 63) ? rank : 63;
                const int recv = __builtin_amdgcn_ds_permute(addr << 2,
                                                             base + (k << 6) + lane);
                if (lane >= cnt && lane < SS && (lane - cnt) < pc) my_nb = recv;
                cnt += pc;                 // uniform
                if (cnt >= SS) break;      // uniform
            }
        }
        if (cnt >= SS) break;
    }

    // Padding: slots past the found count get the first found index (or 0 if none).
    int first = __shfl(my_nb, 0);
    if (first < 0) first = 0;
    if (lane < SS && my_nb < 0) my_nb = first;

    // All 64 lanes fetch slot (lane & 31)'s neighbor index.
    const int n_of = __shfl(my_nb, lane & 31);

    // Gather + write: lanes 0-31 handle channel cc, lanes 32-63 channel cc+1.
    const int s = lane & 31;
    const int chalf = lane >> 5;
    const size_t out_base = (((size_t)b * CH) * MM + m) * SS + s;
    const float* __restrict__ fb = feat + (size_t)b * CC * NN;

    #pragma unroll 2
    for (int cc = 0; cc < CH + 1; cc += 2) {
        const int c = cc + chalf;
        if (c < CH) {
            float v;
            if (c < 3) {
                const float center = (c == 0) ? cx : (c == 1) ? cy : cz;
                v = __fsub_rn(xb[(size_t)n_of * 3 + c], center);
            } else {
                v = fb[(size_t)(c - 3) * NN + n_of];
            }
            out[out_base + (size_t)c * (MM * SS)] = v;
        }
    }
}

extern "C" void kernel_launch(void* const* d_in, const int* in_sizes, int n_in,
                              void* d_out, int out_size, void* d_ws, size_t ws_size,
                              hipStream_t stream) {
    const float* xyz     = (const float*)d_in[0];  // (4,8192,3)
    const float* new_xyz = (const float*)d_in[1];  // (4,4096,3)
    const float* feat    = (const float*)d_in[2];  // (4,64,8192)
    float* out = (float*)d_out;                    // (4,67,4096,32)

    // One wave per query: B*M = 16384 waves; 4 waves per 256-thread block.
    const int total_waves = BB * MM;
    const int blocks = total_waves / 4;
    qg_fused_kernel<<<blocks, 256, 0, stream>>>(xyz, new_xyz, feat, out);
}